// Round 10
// baseline (259.932 us; speedup 1.0000x reference)
//
#include <hip/hip_runtime.h>

#define N_NODES 100000
#define N_EDGES 1000000
#define EPS 1e-5f
#define SLOPE 0.01f
#define NBLK 391    // ceil(N_NODES/256)

typedef int v4i __attribute__((ext_vector_type(4)));

__device__ __forceinline__ void nt_store4(float4* p, float4 v) {
    v4i x = { __float_as_int(v.x), __float_as_int(v.y),
              __float_as_int(v.z), __float_as_int(v.w) };
    __builtin_nontemporal_store(x, (v4i*)p);
}
__device__ __forceinline__ float4 nt_load4(const float4* p) {
    v4i x = __builtin_nontemporal_load((const v4i*)p);
    return make_float4(__int_as_float(x.x), __int_as_float(x.y),
                       __int_as_float(x.z), __int_as_float(x.w));
}

// ---------------------------------------------------------------------------
// ws layout:
//   P        : E * 32 B (32 MB)  {float4 ef; int src; pad} in CSR(dst) order
//   hist     : N ints   [zeroed] in-degree
//   cursor   : N ints   [zeroed] scatter cursor
//   stats    : 32 floats[zeroed] sum[16], sumsq[16]
//   row_part : N ints            block-local exclusive scan of hist
//   bsum     : 512 ints          per-block totals (NBLK used)
// Measured design rules:
//   r1/r3 : random scatter write costs one 64 B line regardless of payload
//           -> scatter whole 32 B payload once; aggregation reads sequential.
//   r4-r7 : 1 thr/node fused gather + x4 ILP unroll is the best gather shape.
//   r8/r9 : intra-kernel grid.sync fusion is NOT coherence-safe on 8-XCD
//           MI355X (garbage / fault). Dispatch boundaries are the fence.
//   r10   : scan2 dispatch deleted (consumers scan bsum in LDS); nt stores
//           for P scatter (HBM 32 B granularity); nt loads for P stream
//           (keep v L2-resident).
// ---------------------------------------------------------------------------

// Exclusive prefix of bsum[0..NBLK) into s_ex[0..512). Needs 256 threads.
__device__ __forceinline__ void scan_bsums(const int* __restrict__ bsum,
                                           int* s_ex /*[512]*/)
{
    int t = threadIdx.x;
    int a = (t < NBLK) ? bsum[t] : 0;
    int b = (t + 256 < NBLK) ? bsum[t + 256] : 0;
    s_ex[t] = a;
    s_ex[t + 256] = b;
    __syncthreads();
    #pragma unroll
    for (int off = 1; off < 512; off <<= 1) {
        int v0 = (t >= off) ? s_ex[t - off] : 0;
        int v1 = (t + 256 >= off) ? s_ex[t + 256 - off] : 0;
        __syncthreads();
        s_ex[t] += v0;
        s_ex[t + 256] += v1;
        __syncthreads();
    }
    int e0 = (t == 0) ? 0 : s_ex[t - 1];   // inclusive -> exclusive shift
    int e1 = s_ex[t + 255];
    __syncthreads();
    s_ex[t] = e0;
    s_ex[t + 256] = e1;
    __syncthreads();
}

// Kernel 1: in-degree histogram (4 edges/thread, int4 loads).
__global__ __launch_bounds__(256) void count_kernel(
    const int* __restrict__ edge_index,
    int* __restrict__ hist)
{
    int i = blockIdx.x * 256 + threadIdx.x;
    if (i >= N_EDGES / 4) return;
    int4 d = *(const int4*)(edge_index + N_EDGES + i * 4);
    atomicAdd(hist + d.x, 1);
    atomicAdd(hist + d.y, 1);
    atomicAdd(hist + d.z, 1);
    atomicAdd(hist + d.w, 1);
}

// Kernel 2: block-local exclusive scan of hist + block sums.
__global__ __launch_bounds__(256) void scan1_kernel(
    const int* __restrict__ hist,
    int* __restrict__ row_part,
    int* __restrict__ bsum)
{
    __shared__ int s[256];
    int tid = threadIdx.x;
    int idx = blockIdx.x * 256 + tid;
    int val = (idx < N_NODES) ? hist[idx] : 0;
    s[tid] = val;
    __syncthreads();
    #pragma unroll
    for (int off = 1; off < 256; off <<= 1) {
        int t = (tid >= off) ? s[tid - off] : 0;
        __syncthreads();
        s[tid] += t;
        __syncthreads();
    }
    if (idx < N_NODES) row_part[idx] = s[tid] - val;
    if (tid == 255) bsum[blockIdx.x] = s[255];
}

// ---------------------------------------------------------------------------
// Kernel 3: scatter FULL edge payload {ef, src} into CSR(dst) slot order.
// Block-local LDS scan of bsum replaces the old scan2 dispatch. Non-temporal
// stores: P is written once and read once next dispatch — bypass L2 and let
// HBM's 32 B granularity avoid full-line RFO/writeback amplification.
// ---------------------------------------------------------------------------
__global__ __launch_bounds__(256) void scatter_kernel(
    const float* __restrict__ efeat,
    const int* __restrict__ edge_index,
    const int* __restrict__ row_part,
    const int* __restrict__ bsum,
    int* __restrict__ cursor,
    float4* __restrict__ P)
{
    __shared__ int s_ex[512];
    scan_bsums(bsum, s_ex);

    int eid = blockIdx.x * 256 + threadIdx.x;
    if (eid >= N_EDGES) return;
    int src = edge_index[eid];
    int dst = edge_index[N_EDGES + eid];
    float4 ef = *(const float4*)(efeat + (size_t)eid * 4);
    int slot = row_part[dst] + s_ex[dst >> 8] + atomicAdd(cursor + dst, 1);
    nt_store4(P + (size_t)2 * slot, ef);
    nt_store4(P + (size_t)2 * slot + 1,
              make_float4(__int_as_float(src), 0.f, 0.f, 0.f));
}

// ---------------------------------------------------------------------------
// Kernel 4 (fused gather + node): 1 thread/node, x4 ILP unroll (r7 body).
// P stream read with non-temporal loads (read-once data; keeps v L2-hot).
// ---------------------------------------------------------------------------
__global__ __launch_bounds__(256) void gather_node_kernel(
    const float* __restrict__ v,
    const float4* __restrict__ P,
    const int* __restrict__ hist,
    const int* __restrict__ row_part,
    const int* __restrict__ bsum,
    const float* __restrict__ enet_w,
    const float* __restrict__ enet_b,
    const float* __restrict__ root,
    const float* __restrict__ bias,
    float* __restrict__ out,
    float* __restrict__ stats)
{
    __shared__ int s_ex[512];
    scan_bsums(bsum, s_ex);

    int n = blockIdx.x * 256 + threadIdx.x;
    bool active = (n < N_NODES);

    float acc[80];
    #pragma unroll
    for (int i = 0; i < 80; ++i) acc[i] = 0.0f;

    int deg = 0, start = 0;
    if (active) {
        start = row_part[n] + s_ex[n >> 8];
        deg = hist[n];
    }

    const float4* pp = P + (size_t)2 * start;
    int j = 0;
    for (; j + 4 <= deg; j += 4) {
        // 8 sequential float4 nt-loads (4 records, 256 B) — issued together
        float4 ef0 = nt_load4(pp + 2*j+0), sp0 = nt_load4(pp + 2*j+1);
        float4 ef1 = nt_load4(pp + 2*j+2), sp1 = nt_load4(pp + 2*j+3);
        float4 ef2 = nt_load4(pp + 2*j+4), sp2 = nt_load4(pp + 2*j+5);
        float4 ef3 = nt_load4(pp + 2*j+6), sp3 = nt_load4(pp + 2*j+7);
        int s0 = __float_as_int(sp0.x);
        int s1 = __float_as_int(sp1.x);
        int s2 = __float_as_int(sp2.x);
        int s3 = __float_as_int(sp3.x);
        const float4* vr0 = (const float4*)(v + (size_t)s0 * 16);
        const float4* vr1 = (const float4*)(v + (size_t)s1 * 16);
        const float4* vr2 = (const float4*)(v + (size_t)s2 * 16);
        const float4* vr3 = (const float4*)(v + (size_t)s3 * 16);
        #pragma unroll
        for (int i = 0; i < 4; ++i) {
            float4 a = vr0[i], b = vr1[i], c = vr2[i], d = vr3[i];
            acc[     i*4+0] += (a.x + b.x) + (c.x + d.x);
            acc[     i*4+1] += (a.y + b.y) + (c.y + d.y);
            acc[     i*4+2] += (a.z + b.z) + (c.z + d.z);
            acc[     i*4+3] += (a.w + b.w) + (c.w + d.w);
            acc[16 + i*4+0] = fmaf(ef0.x, a.x, fmaf(ef1.x, b.x,
                              fmaf(ef2.x, c.x, fmaf(ef3.x, d.x, acc[16 + i*4+0]))));
            acc[16 + i*4+1] = fmaf(ef0.x, a.y, fmaf(ef1.x, b.y,
                              fmaf(ef2.x, c.y, fmaf(ef3.x, d.y, acc[16 + i*4+1]))));
            acc[16 + i*4+2] = fmaf(ef0.x, a.z, fmaf(ef1.x, b.z,
                              fmaf(ef2.x, c.z, fmaf(ef3.x, d.z, acc[16 + i*4+2]))));
            acc[16 + i*4+3] = fmaf(ef0.x, a.w, fmaf(ef1.x, b.w,
                              fmaf(ef2.x, c.w, fmaf(ef3.x, d.w, acc[16 + i*4+3]))));
            acc[32 + i*4+0] = fmaf(ef0.y, a.x, fmaf(ef1.y, b.x,
                              fmaf(ef2.y, c.x, fmaf(ef3.y, d.x, acc[32 + i*4+0]))));
            acc[32 + i*4+1] = fmaf(ef0.y, a.y, fmaf(ef1.y, b.y,
                              fmaf(ef2.y, c.y, fmaf(ef3.y, d.y, acc[32 + i*4+1]))));
            acc[32 + i*4+2] = fmaf(ef0.y, a.z, fmaf(ef1.y, b.z,
                              fmaf(ef2.y, c.z, fmaf(ef3.y, d.z, acc[32 + i*4+2]))));
            acc[32 + i*4+3] = fmaf(ef0.y, a.w, fmaf(ef1.y, b.w,
                              fmaf(ef2.y, c.w, fmaf(ef3.y, d.w, acc[32 + i*4+3]))));
            acc[48 + i*4+0] = fmaf(ef0.z, a.x, fmaf(ef1.z, b.x,
                              fmaf(ef2.z, c.x, fmaf(ef3.z, d.x, acc[48 + i*4+0]))));
            acc[48 + i*4+1] = fmaf(ef0.z, a.y, fmaf(ef1.z, b.y,
                              fmaf(ef2.z, c.y, fmaf(ef3.z, d.y, acc[48 + i*4+1]))));
            acc[48 + i*4+2] = fmaf(ef0.z, a.z, fmaf(ef1.z, b.z,
                              fmaf(ef2.z, c.z, fmaf(ef3.z, d.z, acc[48 + i*4+2]))));
            acc[48 + i*4+3] = fmaf(ef0.z, a.w, fmaf(ef1.z, b.w,
                              fmaf(ef2.z, c.w, fmaf(ef3.z, d.w, acc[48 + i*4+3]))));
            acc[64 + i*4+0] = fmaf(ef0.w, a.x, fmaf(ef1.w, b.x,
                              fmaf(ef2.w, c.x, fmaf(ef3.w, d.x, acc[64 + i*4+0]))));
            acc[64 + i*4+1] = fmaf(ef0.w, a.y, fmaf(ef1.w, b.y,
                              fmaf(ef2.w, c.y, fmaf(ef3.w, d.y, acc[64 + i*4+1]))));
            acc[64 + i*4+2] = fmaf(ef0.w, a.z, fmaf(ef1.w, b.z,
                              fmaf(ef2.w, c.z, fmaf(ef3.w, d.z, acc[64 + i*4+2]))));
            acc[64 + i*4+3] = fmaf(ef0.w, a.w, fmaf(ef1.w, b.w,
                              fmaf(ef2.w, c.w, fmaf(ef3.w, d.w, acc[64 + i*4+3]))));
        }
    }
    for (; j < deg; ++j) {
        float4 ef = nt_load4(pp + 2*j);
        float4 sp = nt_load4(pp + 2*j+1);
        int src = __float_as_int(sp.x);
        const float4* vr = (const float4*)(v + (size_t)src * 16);
        #pragma unroll
        for (int i = 0; i < 4; ++i) {
            float4 a = vr[i];
            acc[     i*4+0] += a.x;
            acc[     i*4+1] += a.y;
            acc[     i*4+2] += a.z;
            acc[     i*4+3] += a.w;
            acc[16 + i*4+0] = fmaf(ef.x, a.x, acc[16 + i*4+0]);
            acc[16 + i*4+1] = fmaf(ef.x, a.y, acc[16 + i*4+1]);
            acc[16 + i*4+2] = fmaf(ef.x, a.z, acc[16 + i*4+2]);
            acc[16 + i*4+3] = fmaf(ef.x, a.w, acc[16 + i*4+3]);
            acc[32 + i*4+0] = fmaf(ef.y, a.x, acc[32 + i*4+0]);
            acc[32 + i*4+1] = fmaf(ef.y, a.y, acc[32 + i*4+1]);
            acc[32 + i*4+2] = fmaf(ef.y, a.z, acc[32 + i*4+2]);
            acc[32 + i*4+3] = fmaf(ef.y, a.w, acc[32 + i*4+3]);
            acc[48 + i*4+0] = fmaf(ef.z, a.x, acc[48 + i*4+0]);
            acc[48 + i*4+1] = fmaf(ef.z, a.y, acc[48 + i*4+1]);
            acc[48 + i*4+2] = fmaf(ef.z, a.z, acc[48 + i*4+2]);
            acc[48 + i*4+3] = fmaf(ef.z, a.w, acc[48 + i*4+3]);
            acc[64 + i*4+0] = fmaf(ef.w, a.x, acc[64 + i*4+0]);
            acc[64 + i*4+1] = fmaf(ef.w, a.y, acc[64 + i*4+1]);
            acc[64 + i*4+2] = fmaf(ef.w, a.z, acc[64 + i*4+2]);
            acc[64 + i*4+3] = fmaf(ef.w, a.w, acc[64 + i*4+3]);
        }
    }

    float val[16];
    if (active) {
        float vn[16];
        #pragma unroll
        for (int i = 0; i < 4; ++i) {
            float4 tv = *(const float4*)(v + (size_t)n * 16 + i * 4);
            vn[4*i+0] = tv.x; vn[4*i+1] = tv.y;
            vn[4*i+2] = tv.z; vn[4*i+3] = tv.w;
        }
        float scale = 1.0f / fmaxf((float)deg, 1.0f);
        #pragma unroll
        for (int o = 0; o < 16; ++o) {
            float a = 0.0f;
            #pragma unroll
            for (int i = 0; i < 16; ++i) {
                a = fmaf(acc[i], enet_b[i * 16 + o], a);           // S0 * B
                #pragma unroll
                for (int k = 0; k < 4; ++k)
                    a = fmaf(acc[16 + k * 16 + i],
                             enet_w[(i * 16 + o) * 4 + k], a);     // Sk * Wk
            }
            a = fmaf(a, scale, bias[o]);
            #pragma unroll
            for (int i = 0; i < 16; ++i)
                a = fmaf(vn[i], root[i * 16 + o], a);
            val[o] = a;
        }
        #pragma unroll
        for (int i = 0; i < 4; ++i)
            *(float4*)(out + (size_t)n * 16 + i * 4) =
                make_float4(val[4*i+0], val[4*i+1], val[4*i+2], val[4*i+3]);
    } else {
        #pragma unroll
        for (int o = 0; o < 16; ++o) val[o] = 0.0f;
    }

    // wave butterfly + LDS reduction of sum / sumsq per column
    float ssum[16], ssq[16];
    #pragma unroll
    for (int o = 0; o < 16; ++o) {
        float a = val[o];
        float b = a * a;
        #pragma unroll
        for (int m = 1; m < 64; m <<= 1) {
            a += __shfl_xor(a, m, 64);
            b += __shfl_xor(b, m, 64);
        }
        ssum[o] = a; ssq[o] = b;
    }
    __shared__ float part[4][32];
    int wave = threadIdx.x >> 6;
    int lane = threadIdx.x & 63;
    if (lane == 0) {
        #pragma unroll
        for (int o = 0; o < 16; ++o) {
            part[wave][o]      = ssum[o];
            part[wave][16 + o] = ssq[o];
        }
    }
    __syncthreads();
    if (threadIdx.x < 32) {
        float t = part[0][threadIdx.x] + part[1][threadIdx.x] +
                  part[2][threadIdx.x] + part[3][threadIdx.x];
        unsafeAtomicAdd(stats + threadIdx.x, t);
    }
}

// Kernel 5: BatchNorm (batch stats) + LeakyReLU, in place, float4-vectorized.
__global__ __launch_bounds__(256) void final_kernel(
    float* __restrict__ out,
    const float* __restrict__ stats,
    const float* __restrict__ gamma,
    const float* __restrict__ beta)
{
    int idx = blockIdx.x * 256 + threadIdx.x;      // float4 index
    if (idx >= N_NODES * 4) return;
    int o0 = (idx & 3) << 2;
    const float invN = 1.0f / (float)N_NODES;
    float4 x = *((const float4*)out + idx);
    float xs[4] = {x.x, x.y, x.z, x.w};
    float r[4];
    #pragma unroll
    for (int u = 0; u < 4; ++u) {
        int o = o0 + u;
        float mu = stats[o] * invN;
        float var = fmaxf(stats[16 + o] * invN - mu * mu, 0.0f);
        float y = fmaf(gamma[o] * (xs[u] - mu), rsqrtf(var + EPS), beta[o]);
        r[u] = (y >= 0.0f) ? y : SLOPE * y;
    }
    *((float4*)out + idx) = make_float4(r[0], r[1], r[2], r[3]);
}

extern "C" void kernel_launch(void* const* d_in, const int* in_sizes, int n_in,
                              void* d_out, int out_size, void* d_ws, size_t ws_size,
                              hipStream_t stream)
{
    const float* v = (const float*)d_in[0];
    const float* e = (const float*)d_in[1];
    const int* edge_index = (const int*)d_in[2];
    const float* enet_w = (const float*)d_in[3];
    const float* enet_b = (const float*)d_in[4];
    const float* root = (const float*)d_in[5];
    const float* bias = (const float*)d_in[6];
    const float* gamma = (const float*)d_in[7];
    const float* beta = (const float*)d_in[8];
    float* out = (float*)d_out;

    char* ws = (char*)d_ws;
    float4* P        = (float4*)ws;                 ws += (size_t)N_EDGES * 32;
    int*    hist     = (int*)ws;                    ws += (size_t)N_NODES * 4;
    int*    cursor   = (int*)ws;                    ws += (size_t)N_NODES * 4;
    float*  stats    = (float*)ws;                  ws += 32 * 4;
    int*    row_part = (int*)ws;                    ws += (size_t)N_NODES * 4;
    int*    bsum     = (int*)ws;

    // zero hist + cursor + stats (contiguous)
    hipMemsetAsync(hist, 0, (size_t)N_NODES * 4 * 2 + 32 * 4, stream);

    count_kernel<<<(N_EDGES / 4 + 255) / 256, 256, 0, stream>>>(edge_index, hist);
    scan1_kernel<<<NBLK, 256, 0, stream>>>(hist, row_part, bsum);
    scatter_kernel<<<(N_EDGES + 255) / 256, 256, 0, stream>>>(
        e, edge_index, row_part, bsum, cursor, P);
    gather_node_kernel<<<NBLK, 256, 0, stream>>>(
        v, P, hist, row_part, bsum, enet_w, enet_b, root, bias, out, stats);
    final_kernel<<<(N_NODES * 4 + 255) / 256, 256, 0, stream>>>(
        out, stats, gamma, beta);
}

// Round 11
// 233.845 us; speedup vs baseline: 1.1116x; 1.1116x over previous
//
#include <hip/hip_runtime.h>

#define N_NODES 100000
#define N_EDGES 1000000
#define EPS 1e-5f
#define SLOPE 0.01f
#define NBLK 391    // ceil(N_NODES/256)

typedef int v4i __attribute__((ext_vector_type(4)));

__device__ __forceinline__ float4 nt_load4(const float4* p) {
    v4i x = __builtin_nontemporal_load((const v4i*)p);
    return make_float4(__int_as_float(x.x), __int_as_float(x.y),
                       __int_as_float(x.z), __int_as_float(x.w));
}

// ---------------------------------------------------------------------------
// ws layout:
//   P        : E * 32 B (32 MB)  {float4 ef; int src; pad} in CSR(dst) order
//   hist     : N ints   [zeroed] in-degree
//   cursor   : N ints   [zeroed] scatter cursor
//   stats    : 32 floats[zeroed] sum[16], sumsq[16]
//   row_part : N ints            block-local exclusive scan of hist
//   bsum     : 512 ints          per-block totals (NBLK used)
// Measured design rules:
//   r1/r3 : random scatter write costs one 64 B line regardless of payload
//           -> scatter whole 32 B payload once; aggregation reads sequential.
//   r4-r7 : 1 thr/node fused gather + x4 ILP unroll is the best gather shape.
//   r8/r9 : intra-kernel grid.sync fusion is NOT coherence-safe on 8-XCD
//           MI355X (garbage / fault). Dispatch boundaries are the fence.
//   r10   : nt stores for the scatter REGRESSED (WRITE 64->74 MB, 57->80 us):
//           L2 was already merging same-line CSR writes; bypassing it costs.
//           Plain cached stores are optimal for the random scatter.
//   r11   : keep scan2-deletion (LDS scan in consumers) + nt P-loads.
// ---------------------------------------------------------------------------

// Exclusive prefix of bsum[0..NBLK) into s_ex[0..512). Needs 256 threads.
__device__ __forceinline__ void scan_bsums(const int* __restrict__ bsum,
                                           int* s_ex /*[512]*/)
{
    int t = threadIdx.x;
    int a = (t < NBLK) ? bsum[t] : 0;
    int b = (t + 256 < NBLK) ? bsum[t + 256] : 0;
    s_ex[t] = a;
    s_ex[t + 256] = b;
    __syncthreads();
    #pragma unroll
    for (int off = 1; off < 512; off <<= 1) {
        int v0 = (t >= off) ? s_ex[t - off] : 0;
        int v1 = (t + 256 >= off) ? s_ex[t + 256 - off] : 0;
        __syncthreads();
        s_ex[t] += v0;
        s_ex[t + 256] += v1;
        __syncthreads();
    }
    int e0 = (t == 0) ? 0 : s_ex[t - 1];   // inclusive -> exclusive shift
    int e1 = s_ex[t + 255];
    __syncthreads();
    s_ex[t] = e0;
    s_ex[t + 256] = e1;
    __syncthreads();
}

// Kernel 1: in-degree histogram (4 edges/thread, int4 loads).
__global__ __launch_bounds__(256) void count_kernel(
    const int* __restrict__ edge_index,
    int* __restrict__ hist)
{
    int i = blockIdx.x * 256 + threadIdx.x;
    if (i >= N_EDGES / 4) return;
    int4 d = *(const int4*)(edge_index + N_EDGES + i * 4);
    atomicAdd(hist + d.x, 1);
    atomicAdd(hist + d.y, 1);
    atomicAdd(hist + d.z, 1);
    atomicAdd(hist + d.w, 1);
}

// Kernel 2: block-local exclusive scan of hist + block sums.
__global__ __launch_bounds__(256) void scan1_kernel(
    const int* __restrict__ hist,
    int* __restrict__ row_part,
    int* __restrict__ bsum)
{
    __shared__ int s[256];
    int tid = threadIdx.x;
    int idx = blockIdx.x * 256 + tid;
    int val = (idx < N_NODES) ? hist[idx] : 0;
    s[tid] = val;
    __syncthreads();
    #pragma unroll
    for (int off = 1; off < 256; off <<= 1) {
        int t = (tid >= off) ? s[tid - off] : 0;
        __syncthreads();
        s[tid] += t;
        __syncthreads();
    }
    if (idx < N_NODES) row_part[idx] = s[tid] - val;
    if (tid == 255) bsum[blockIdx.x] = s[255];
}

// ---------------------------------------------------------------------------
// Kernel 3: scatter FULL edge payload {ef, src} into CSR(dst) slot order.
// Block-local LDS scan of bsum replaces the old scan2 dispatch. PLAIN cached
// stores (r10: nt stores regressed — L2 merges same-line CSR writes).
// ---------------------------------------------------------------------------
__global__ __launch_bounds__(256) void scatter_kernel(
    const float* __restrict__ efeat,
    const int* __restrict__ edge_index,
    const int* __restrict__ row_part,
    const int* __restrict__ bsum,
    int* __restrict__ cursor,
    float4* __restrict__ P)
{
    __shared__ int s_ex[512];
    scan_bsums(bsum, s_ex);

    int eid = blockIdx.x * 256 + threadIdx.x;
    if (eid >= N_EDGES) return;
    int src = edge_index[eid];
    int dst = edge_index[N_EDGES + eid];
    float4 ef = *(const float4*)(efeat + (size_t)eid * 4);
    int slot = row_part[dst] + s_ex[dst >> 8] + atomicAdd(cursor + dst, 1);
    P[(size_t)2 * slot]     = ef;
    P[(size_t)2 * slot + 1] = make_float4(__int_as_float(src), 0.f, 0.f, 0.f);
}

// ---------------------------------------------------------------------------
// Kernel 4 (fused gather + node): 1 thread/node, x4 ILP unroll (r7 body).
// P stream read with non-temporal loads (read-once data; keeps v L2-hot).
// ---------------------------------------------------------------------------
__global__ __launch_bounds__(256) void gather_node_kernel(
    const float* __restrict__ v,
    const float4* __restrict__ P,
    const int* __restrict__ hist,
    const int* __restrict__ row_part,
    const int* __restrict__ bsum,
    const float* __restrict__ enet_w,
    const float* __restrict__ enet_b,
    const float* __restrict__ root,
    const float* __restrict__ bias,
    float* __restrict__ out,
    float* __restrict__ stats)
{
    __shared__ int s_ex[512];
    scan_bsums(bsum, s_ex);

    int n = blockIdx.x * 256 + threadIdx.x;
    bool active = (n < N_NODES);

    float acc[80];
    #pragma unroll
    for (int i = 0; i < 80; ++i) acc[i] = 0.0f;

    int deg = 0, start = 0;
    if (active) {
        start = row_part[n] + s_ex[n >> 8];
        deg = hist[n];
    }

    const float4* pp = P + (size_t)2 * start;
    int j = 0;
    for (; j + 4 <= deg; j += 4) {
        // 8 sequential float4 nt-loads (4 records, 256 B) — issued together
        float4 ef0 = nt_load4(pp + 2*j+0), sp0 = nt_load4(pp + 2*j+1);
        float4 ef1 = nt_load4(pp + 2*j+2), sp1 = nt_load4(pp + 2*j+3);
        float4 ef2 = nt_load4(pp + 2*j+4), sp2 = nt_load4(pp + 2*j+5);
        float4 ef3 = nt_load4(pp + 2*j+6), sp3 = nt_load4(pp + 2*j+7);
        int s0 = __float_as_int(sp0.x);
        int s1 = __float_as_int(sp1.x);
        int s2 = __float_as_int(sp2.x);
        int s3 = __float_as_int(sp3.x);
        const float4* vr0 = (const float4*)(v + (size_t)s0 * 16);
        const float4* vr1 = (const float4*)(v + (size_t)s1 * 16);
        const float4* vr2 = (const float4*)(v + (size_t)s2 * 16);
        const float4* vr3 = (const float4*)(v + (size_t)s3 * 16);
        #pragma unroll
        for (int i = 0; i < 4; ++i) {
            float4 a = vr0[i], b = vr1[i], c = vr2[i], d = vr3[i];
            acc[     i*4+0] += (a.x + b.x) + (c.x + d.x);
            acc[     i*4+1] += (a.y + b.y) + (c.y + d.y);
            acc[     i*4+2] += (a.z + b.z) + (c.z + d.z);
            acc[     i*4+3] += (a.w + b.w) + (c.w + d.w);
            acc[16 + i*4+0] = fmaf(ef0.x, a.x, fmaf(ef1.x, b.x,
                              fmaf(ef2.x, c.x, fmaf(ef3.x, d.x, acc[16 + i*4+0]))));
            acc[16 + i*4+1] = fmaf(ef0.x, a.y, fmaf(ef1.x, b.y,
                              fmaf(ef2.x, c.y, fmaf(ef3.x, d.y, acc[16 + i*4+1]))));
            acc[16 + i*4+2] = fmaf(ef0.x, a.z, fmaf(ef1.x, b.z,
                              fmaf(ef2.x, c.z, fmaf(ef3.x, d.z, acc[16 + i*4+2]))));
            acc[16 + i*4+3] = fmaf(ef0.x, a.w, fmaf(ef1.x, b.w,
                              fmaf(ef2.x, c.w, fmaf(ef3.x, d.w, acc[16 + i*4+3]))));
            acc[32 + i*4+0] = fmaf(ef0.y, a.x, fmaf(ef1.y, b.x,
                              fmaf(ef2.y, c.x, fmaf(ef3.y, d.x, acc[32 + i*4+0]))));
            acc[32 + i*4+1] = fmaf(ef0.y, a.y, fmaf(ef1.y, b.y,
                              fmaf(ef2.y, c.y, fmaf(ef3.y, d.y, acc[32 + i*4+1]))));
            acc[32 + i*4+2] = fmaf(ef0.y, a.z, fmaf(ef1.y, b.z,
                              fmaf(ef2.y, c.z, fmaf(ef3.y, d.z, acc[32 + i*4+2]))));
            acc[32 + i*4+3] = fmaf(ef0.y, a.w, fmaf(ef1.y, b.w,
                              fmaf(ef2.y, c.w, fmaf(ef3.y, d.w, acc[32 + i*4+3]))));
            acc[48 + i*4+0] = fmaf(ef0.z, a.x, fmaf(ef1.z, b.x,
                              fmaf(ef2.z, c.x, fmaf(ef3.z, d.x, acc[48 + i*4+0]))));
            acc[48 + i*4+1] = fmaf(ef0.z, a.y, fmaf(ef1.z, b.y,
                              fmaf(ef2.z, c.y, fmaf(ef3.z, d.y, acc[48 + i*4+1]))));
            acc[48 + i*4+2] = fmaf(ef0.z, a.z, fmaf(ef1.z, b.z,
                              fmaf(ef2.z, c.z, fmaf(ef3.z, d.z, acc[48 + i*4+2]))));
            acc[48 + i*4+3] = fmaf(ef0.z, a.w, fmaf(ef1.z, b.w,
                              fmaf(ef2.z, c.w, fmaf(ef3.z, d.w, acc[48 + i*4+3]))));
            acc[64 + i*4+0] = fmaf(ef0.w, a.x, fmaf(ef1.w, b.x,
                              fmaf(ef2.w, c.x, fmaf(ef3.w, d.x, acc[64 + i*4+0]))));
            acc[64 + i*4+1] = fmaf(ef0.w, a.y, fmaf(ef1.w, b.y,
                              fmaf(ef2.w, c.y, fmaf(ef3.w, d.y, acc[64 + i*4+1]))));
            acc[64 + i*4+2] = fmaf(ef0.w, a.z, fmaf(ef1.w, b.z,
                              fmaf(ef2.w, c.z, fmaf(ef3.w, d.z, acc[64 + i*4+2]))));
            acc[64 + i*4+3] = fmaf(ef0.w, a.w, fmaf(ef1.w, b.w,
                              fmaf(ef2.w, c.w, fmaf(ef3.w, d.w, acc[64 + i*4+3]))));
        }
    }
    for (; j < deg; ++j) {
        float4 ef = nt_load4(pp + 2*j);
        float4 sp = nt_load4(pp + 2*j+1);
        int src = __float_as_int(sp.x);
        const float4* vr = (const float4*)(v + (size_t)src * 16);
        #pragma unroll
        for (int i = 0; i < 4; ++i) {
            float4 a = vr[i];
            acc[     i*4+0] += a.x;
            acc[     i*4+1] += a.y;
            acc[     i*4+2] += a.z;
            acc[     i*4+3] += a.w;
            acc[16 + i*4+0] = fmaf(ef.x, a.x, acc[16 + i*4+0]);
            acc[16 + i*4+1] = fmaf(ef.x, a.y, acc[16 + i*4+1]);
            acc[16 + i*4+2] = fmaf(ef.x, a.z, acc[16 + i*4+2]);
            acc[16 + i*4+3] = fmaf(ef.x, a.w, acc[16 + i*4+3]);
            acc[32 + i*4+0] = fmaf(ef.y, a.x, acc[32 + i*4+0]);
            acc[32 + i*4+1] = fmaf(ef.y, a.y, acc[32 + i*4+1]);
            acc[32 + i*4+2] = fmaf(ef.y, a.z, acc[32 + i*4+2]);
            acc[32 + i*4+3] = fmaf(ef.y, a.w, acc[32 + i*4+3]);
            acc[48 + i*4+0] = fmaf(ef.z, a.x, acc[48 + i*4+0]);
            acc[48 + i*4+1] = fmaf(ef.z, a.y, acc[48 + i*4+1]);
            acc[48 + i*4+2] = fmaf(ef.z, a.z, acc[48 + i*4+2]);
            acc[48 + i*4+3] = fmaf(ef.z, a.w, acc[48 + i*4+3]);
            acc[64 + i*4+0] = fmaf(ef.w, a.x, acc[64 + i*4+0]);
            acc[64 + i*4+1] = fmaf(ef.w, a.y, acc[64 + i*4+1]);
            acc[64 + i*4+2] = fmaf(ef.w, a.z, acc[64 + i*4+2]);
            acc[64 + i*4+3] = fmaf(ef.w, a.w, acc[64 + i*4+3]);
        }
    }

    float val[16];
    if (active) {
        float vn[16];
        #pragma unroll
        for (int i = 0; i < 4; ++i) {
            float4 tv = *(const float4*)(v + (size_t)n * 16 + i * 4);
            vn[4*i+0] = tv.x; vn[4*i+1] = tv.y;
            vn[4*i+2] = tv.z; vn[4*i+3] = tv.w;
        }
        float scale = 1.0f / fmaxf((float)deg, 1.0f);
        #pragma unroll
        for (int o = 0; o < 16; ++o) {
            float a = 0.0f;
            #pragma unroll
            for (int i = 0; i < 16; ++i) {
                a = fmaf(acc[i], enet_b[i * 16 + o], a);           // S0 * B
                #pragma unroll
                for (int k = 0; k < 4; ++k)
                    a = fmaf(acc[16 + k * 16 + i],
                             enet_w[(i * 16 + o) * 4 + k], a);     // Sk * Wk
            }
            a = fmaf(a, scale, bias[o]);
            #pragma unroll
            for (int i = 0; i < 16; ++i)
                a = fmaf(vn[i], root[i * 16 + o], a);
            val[o] = a;
        }
        #pragma unroll
        for (int i = 0; i < 4; ++i)
            *(float4*)(out + (size_t)n * 16 + i * 4) =
                make_float4(val[4*i+0], val[4*i+1], val[4*i+2], val[4*i+3]);
    } else {
        #pragma unroll
        for (int o = 0; o < 16; ++o) val[o] = 0.0f;
    }

    // wave butterfly + LDS reduction of sum / sumsq per column
    float ssum[16], ssq[16];
    #pragma unroll
    for (int o = 0; o < 16; ++o) {
        float a = val[o];
        float b = a * a;
        #pragma unroll
        for (int m = 1; m < 64; m <<= 1) {
            a += __shfl_xor(a, m, 64);
            b += __shfl_xor(b, m, 64);
        }
        ssum[o] = a; ssq[o] = b;
    }
    __shared__ float part[4][32];
    int wave = threadIdx.x >> 6;
    int lane = threadIdx.x & 63;
    if (lane == 0) {
        #pragma unroll
        for (int o = 0; o < 16; ++o) {
            part[wave][o]      = ssum[o];
            part[wave][16 + o] = ssq[o];
        }
    }
    __syncthreads();
    if (threadIdx.x < 32) {
        float t = part[0][threadIdx.x] + part[1][threadIdx.x] +
                  part[2][threadIdx.x] + part[3][threadIdx.x];
        unsafeAtomicAdd(stats + threadIdx.x, t);
    }
}

// Kernel 5: BatchNorm (batch stats) + LeakyReLU, in place, float4-vectorized.
__global__ __launch_bounds__(256) void final_kernel(
    float* __restrict__ out,
    const float* __restrict__ stats,
    const float* __restrict__ gamma,
    const float* __restrict__ beta)
{
    int idx = blockIdx.x * 256 + threadIdx.x;      // float4 index
    if (idx >= N_NODES * 4) return;
    int o0 = (idx & 3) << 2;
    const float invN = 1.0f / (float)N_NODES;
    float4 x = *((const float4*)out + idx);
    float xs[4] = {x.x, x.y, x.z, x.w};
    float r[4];
    #pragma unroll
    for (int u = 0; u < 4; ++u) {
        int o = o0 + u;
        float mu = stats[o] * invN;
        float var = fmaxf(stats[16 + o] * invN - mu * mu, 0.0f);
        float y = fmaf(gamma[o] * (xs[u] - mu), rsqrtf(var + EPS), beta[o]);
        r[u] = (y >= 0.0f) ? y : SLOPE * y;
    }
    *((float4*)out + idx) = make_float4(r[0], r[1], r[2], r[3]);
}

extern "C" void kernel_launch(void* const* d_in, const int* in_sizes, int n_in,
                              void* d_out, int out_size, void* d_ws, size_t ws_size,
                              hipStream_t stream)
{
    const float* v = (const float*)d_in[0];
    const float* e = (const float*)d_in[1];
    const int* edge_index = (const int*)d_in[2];
    const float* enet_w = (const float*)d_in[3];
    const float* enet_b = (const float*)d_in[4];
    const float* root = (const float*)d_in[5];
    const float* bias = (const float*)d_in[6];
    const float* gamma = (const float*)d_in[7];
    const float* beta = (const float*)d_in[8];
    float* out = (float*)d_out;

    char* ws = (char*)d_ws;
    float4* P        = (float4*)ws;                 ws += (size_t)N_EDGES * 32;
    int*    hist     = (int*)ws;                    ws += (size_t)N_NODES * 4;
    int*    cursor   = (int*)ws;                    ws += (size_t)N_NODES * 4;
    float*  stats    = (float*)ws;                  ws += 32 * 4;
    int*    row_part = (int*)ws;                    ws += (size_t)N_NODES * 4;
    int*    bsum     = (int*)ws;

    // zero hist + cursor + stats (contiguous)
    hipMemsetAsync(hist, 0, (size_t)N_NODES * 4 * 2 + 32 * 4, stream);

    count_kernel<<<(N_EDGES / 4 + 255) / 256, 256, 0, stream>>>(edge_index, hist);
    scan1_kernel<<<NBLK, 256, 0, stream>>>(hist, row_part, bsum);
    scatter_kernel<<<(N_EDGES + 255) / 256, 256, 0, stream>>>(
        e, edge_index, row_part, bsum, cursor, P);
    gather_node_kernel<<<NBLK, 256, 0, stream>>>(
        v, P, hist, row_part, bsum, enet_w, enet_b, root, bias, out, stats);
    final_kernel<<<(N_NODES * 4 + 255) / 256, 256, 0, stream>>>(
        out, stats, gamma, beta);
}